// Round 4
// baseline (280.587 us; speedup 1.0000x reference)
//
#include <hip/hip_runtime.h>
#include <math.h>

#define NTOK   16384
#define DDIM   2048
#define EDIM   128
#define HDIM   128
#define TOKT   64
#define NRND   16            // rounds of 128 k each
#define KRND   128

typedef __attribute__((ext_vector_type(8)))  _Float16 half8;
typedef __attribute__((ext_vector_type(4)))  float    f32x4;
typedef __attribute__((ext_vector_type(16))) float    f32x16;

#define MFMA32 __builtin_amdgcn_mfma_f32_32x32x16_f16

// b32-granule XOR swizzle for epilogue A[64][128]: conflict-free row+column.
__device__ __forceinline__ int swz(int t, int e) {
  return t * EDIM + ((e & 96) | ((e ^ t) & 31));
}

__device__ __forceinline__ void cvt8(const float4& a, const float4& b,
                                     half8& h, half8& l) {
#pragma unroll
  for (int m = 0; m < 4; ++m) {
    const float v = (&a.x)[m];
    const _Float16 hv = (_Float16)v;
    h[m] = hv; l[m] = (_Float16)((v - (float)hv) * 2048.0f);
  }
#pragma unroll
  for (int m = 0; m < 4; ++m) {
    const float v = (&b.x)[m];
    const _Float16 hv = (_Float16)v;
    h[m + 4] = hv; l[m + 4] = (_Float16)((v - (float)hv) * 2048.0f);
  }
}

// ---- W pre-convert: 32x32x16-fragment-ordered f16 hi/lo planes ----
// elem idx -> (nt, ks, lane, j); lane holds B[k=ks*16+(lane>>5)*8+j][n=nt*32+(lane&31)]
// = Wr[n][k], scaled by 32 (hi) and 32*2048 (lo) to dodge f16 denormals.
__global__ __launch_bounds__(256)
void conv_w(const float* __restrict__ Wr,
            _Float16* __restrict__ wh, _Float16* __restrict__ wl) {
  const int idx  = (int)blockIdx.x * 256 + (int)threadIdx.x;  // 0..32767
  const int lane = idx & 63;
  const int ks   = (idx >> 6) & 127;
  const int nt   = idx >> 13;                                 // 0..3
  const int n    = nt * 32 + (lane & 31);
  const int k0   = ks * 16 + (lane >> 5) * 8;
  half8 h, l;
#pragma unroll
  for (int j = 0; j < 8; ++j) {
    const float w = Wr[(size_t)n * DDIM + k0 + j] * 32.0f;
    const _Float16 hh = (_Float16)w;
    h[j] = hh;
    l[j] = (_Float16)((w - (float)hh) * 2048.0f);
  }
  *(half8*)(wh + (size_t)idx * 8) = h;
  *(half8*)(wl + (size_t)idx * 8) = l;
}

__global__ __launch_bounds__(512, 2)
void fused_router(const float* __restrict__ x,
                  const _Float16* __restrict__ wsh,
                  const _Float16* __restrict__ wsl,
                  const float* __restrict__ Wd,
                  const float* __restrict__ gamma,
                  const float* __restrict__ beta,
                  const float* __restrict__ rnn,
                  const float* __restrict__ gum,
                  float* __restrict__ outb,
                  float* __restrict__ outa) {
  // GEMM phase: x ONLY in LDS, double-buffered 2 x 32 KB, one barrier/round.
  //   frag region (s,mt,pl) at ((s*2+mt)*2+pl)*1024; within region, 16-B slot
  //   index = (koct*32+row) ^ s  (read: lane ^ s) -- conflict-free both sides.
  // W comes straight from global workspace (fragment-ordered, coalesced).
  // Epilogue overlays: A = bytes [0,32K), G4 = [32K,64K).
  __shared__ char smraw[65536];
  char* const sm = smraw;
  float* const A  = (float*)smraw;
  float* const G4 = (float*)(smraw + 32768);

  const int tid  = (int)threadIdx.x;
  const int wv   = __builtin_amdgcn_readfirstlane(tid >> 6);  // 0..7
  const int lane = tid & 63;
  const int t0   = (int)blockIdx.x * TOKT;

  // wave -> one 32x32 C tile: mt = wv>>2 (token half), nt = wv&3 (e quarter)
  const int mt = wv >> 2;
  const int nt = wv & 3;

  // x staging: thread -> (token, kstep-slice of 16 k)
  const int s_tok = (tid & 7) + ((tid >> 6) << 3);   // 8 tokens per wave
  const int s_s   = (tid >> 3) & 7;                  // kstep within round
  const int s_row = s_tok & 31;
  const int s_mt  = s_tok >> 5;
  const float* xg = x + (size_t)(t0 + s_tok) * DDIM + s_s * 16;
  const int wbase = (s_s * 2 + s_mt) * 2048;               // + pl*1024
  const int widx0 = (((0 * 32 + s_row) ^ s_s) * 16);
  const int widx1 = (((1 * 32 + s_row) ^ s_s) * 16);

  // W direct-to-reg: elem offset = ((nt*128 + ks)*64 + lane)*8
  const size_t wbf = (size_t)nt * 65536 + (size_t)lane * 8;

  f32x16 hh, cr;
#pragma unroll
  for (int g = 0; g < 16; ++g) { hh[g] = 0.0f; cr[g] = 0.0f; }

  // ---- prologue: stage round 0 into buffer 0 ----
  {
    const float4 a0 = *(const float4*)(xg + 0);
    const float4 a1 = *(const float4*)(xg + 4);
    const float4 a2 = *(const float4*)(xg + 8);
    const float4 a3 = *(const float4*)(xg + 12);
    half8 h0, l0, h1, l1;
    cvt8(a0, a1, h0, l0);
    cvt8(a2, a3, h1, l1);
    char* dst = sm;
    *(half8*)(dst + wbase + widx0)        = h0;
    *(half8*)(dst + wbase + 1024 + widx0) = l0;
    *(half8*)(dst + wbase + widx1)        = h1;
    *(half8*)(dst + wbase + 1024 + widx1) = l1;
  }

  for (int r = 0; r < NRND; ++r) {
    __syncthreads();                       // buf (r&1) visible; (r&1)^1 free
    float4 p0, p1, p2, p3;
    if (r + 1 < NRND) {                    // issue next-round x loads early
      const float* xn = xg + (r + 1) * KRND;
      p0 = *(const float4*)(xn + 0);
      p1 = *(const float4*)(xn + 4);
      p2 = *(const float4*)(xn + 8);
      p3 = *(const float4*)(xn + 12);
    }
    const char* bb = sm + (r & 1) * 32768;
#pragma unroll
    for (int s = 0; s < 8; ++s) {
      const int fb = (s * 2 + mt) * 2048;
      const int ai = (lane ^ s) * 16;
      const half8 ah = *(const half8*)(bb + fb + ai);
      const half8 al = *(const half8*)(bb + fb + 1024 + ai);
      const size_t wo = wbf + (size_t)(r * 8 + s) * 512;
      const half8 bh = *(const half8*)(wsh + wo);
      const half8 bl = *(const half8*)(wsl + wo);
      hh = MFMA32(ah, bh, hh, 0, 0, 0);
      cr = MFMA32(ah, bl, cr, 0, 0, 0);
      cr = MFMA32(al, bh, cr, 0, 0, 0);
    }
    if (r + 1 < NRND) {                    // convert + write into free buffer
      half8 h0, l0, h1, l1;
      cvt8(p0, p1, h0, l0);
      cvt8(p2, p3, h1, l1);
      char* dst = sm + ((r + 1) & 1) * 32768;
      *(half8*)(dst + wbase + widx0)        = h0;
      *(half8*)(dst + wbase + 1024 + widx0) = l0;
      *(half8*)(dst + wbase + widx1)        = h1;
      *(half8*)(dst + wbase + 1024 + widx1) = l1;
    }
  }
  __syncthreads();                         // GEMM LDS dead

  // ---- unscale + rnn into A ----
  // 32x32 C/D layout: col = lane&31, row = (g&3) + 8*(g>>2) + 4*(lane>>5)
  {
    const int e = nt * 32 + (lane & 31);
    const float rv = rnn[e];
#pragma unroll
    for (int g = 0; g < 16; ++g) {
      const int row = (g & 3) + 8 * (g >> 2) + 4 * (lane >> 5);
      A[swz(mt * 32 + row, e)] =
          hh[g] * (1.0f / 32.0f) + cr[g] * (1.0f / 65536.0f) + rv;
    }
  }
  __syncthreads();

  // ---- LayerNorm + exact GELU: 8 tokens per wave; G -> G4 (float4-swizzled) ----
  {
    const float gm0 = gamma[lane], gm1 = gamma[lane + 64];
    const float bt0 = beta[lane],  bt1 = beta[lane + 64];
    for (int tt = wv * 8; tt < wv * 8 + 8; ++tt) {
      const float v0 = A[swz(tt, lane)];
      const float v1 = A[swz(tt, lane + 64)];
      float s = v0 + v1;
#pragma unroll
      for (int m = 32; m; m >>= 1) s += __shfl_xor(s, m);
      const float mu = s * (1.0f / 128.0f);
      const float d0 = v0 - mu, d1 = v1 - mu;
      float q = d0 * d0 + d1 * d1;
#pragma unroll
      for (int m = 32; m; m >>= 1) q += __shfl_xor(q, m);
      const float rstd = 1.0f / sqrtf(q * (1.0f / 128.0f) + 1e-5f);
      const float h0v = d0 * rstd * gm0 + bt0;
      const float h1v = d1 * rstd * gm1 + bt1;
      const float g0 = 0.5f * h0v * (1.0f + erff(h0v * 0.70710678118654752f));
      const float g1 = 0.5f * h1v * (1.0f + erff(h1v * 0.70710678118654752f));
      const int e0a = lane, e1a = lane + 64;
      G4[(tt * 32 + (((e0a >> 2) ^ (tt & 31)))) * 4 + (e0a & 3)] = g0;
      G4[(tt * 32 + (((e1a >> 2) ^ (tt & 31)))) * 4 + (e1a & 3)] = g1;
    }
  }
  __syncthreads();

  // ---- decoder GEMM: wave = 16 h-rows x 64 tokens (lane = token) ----
  {
    const int rbase = wv * 16;
    float acc2[16];
#pragma unroll
    for (int j = 0; j < 16; ++j) acc2[j] = 0.0f;
    const float4* wd4 = (const float4*)(Wd + (size_t)rbase * EDIM);  // uniform
#pragma unroll 2
    for (int kg = 0; kg < EDIM / 4; ++kg) {
      const float4 gv = *(const float4*)&G4[(lane * 32 + (kg ^ (lane & 31))) * 4];
#pragma unroll
      for (int j = 0; j < 16; ++j) {
        const float4 w = wd4[(size_t)j * (EDIM / 4) + kg];
        acc2[j] = fmaf(gv.x, w.x,
                  fmaf(gv.y, w.y,
                  fmaf(gv.z, w.z,
                  fmaf(gv.w, w.w, acc2[j]))));
      }
    }
    __syncthreads();                 // all LN reads of A done block-wide
#pragma unroll
    for (int j = 0; j < 16; ++j) A[swz(lane, rbase + j)] = acc2[j];
  }
  __syncthreads();

  // ---- gumbel-sigmoid, exact top-k (value then lower-index), output ----
  for (int tt = wv * 8; tt < wv * 8 + 8; ++tt) {
    const size_t T = (size_t)(t0 + tt);
    const float l0 = A[swz(tt, lane)];
    const float l1 = A[swz(tt, lane + 64)];
    const float gn0 = gum[T * HDIM + lane];
    const float gn1 = gum[T * HDIM + lane + 64];
    const float z0 = (l0 + gn0 + 3.0f) * 2.5f;
    const float z1 = (l1 + gn1 + 3.0f) * 2.5f;
    const float ba0 = 1.0f / (1.0f + expf(-z0));
    const float ba1 = 1.0f / (1.0f + expf(-z1));
    const unsigned ub0 = __float_as_uint(ba0);   // ba in (0,1]: bits monotone
    const unsigned ub1 = __float_as_uint(ba1);
    const int r0 = ba0 > 0.5f;                   // round: 0.5 -> 0
    const int r1 = ba1 > 0.5f;
    const int cnt = __popcll(__ballot(r0)) + __popcll(__ballot(r1));
    float bin0, bin1;
    if (cnt > 32) {
      unsigned v = 0u;                            // radix-select 32nd largest
#pragma unroll
      for (int b = 29; b >= 0; --b) {
        const unsigned cand = v | (1u << b);
        const int cc = __popcll(__ballot(ub0 >= cand)) + __popcll(__ballot(ub1 >= cand));
        if (cc >= 32) v = cand;
      }
      const int cgt = __popcll(__ballot(ub0 > v)) + __popcll(__ballot(ub1 > v));
      const int r = 32 - cgt;                     // tied slots; lower index wins
      const unsigned long long t0b = __ballot(ub0 == v);
      const unsigned long long t1b = __ballot(ub1 == v);
      const int n0 = __popcll(t0b);
      const unsigned long long mlt = (1ull << lane) - 1ull;
      const int rk0 = __popcll(t0b & mlt);
      const int rk1 = n0 + __popcll(t1b & mlt);
      bin0 = (ub0 > v || (ub0 == v && rk0 < r)) ? 1.0f : 0.0f;
      bin1 = (ub1 > v || (ub1 == v && rk1 < r)) ? 1.0f : 0.0f;
    } else if (cnt == 0) {
      float m = fmaxf(ba0, ba1);
#pragma unroll
      for (int mm = 32; mm; mm >>= 1) m = fmaxf(m, __shfl_xor(m, mm));
      const unsigned long long e0b = __ballot(ba0 == m);
      const unsigned long long e1b = __ballot(ba1 == m);
      const int hstar = e0b ? (__ffsll((unsigned long long)e0b) - 1)
                            : (64 + __ffsll((unsigned long long)e1b) - 1);
      bin0 = (lane == hstar) ? 1.0f : 0.0f;
      bin1 = (lane + 64 == hstar) ? 1.0f : 0.0f;
    } else {
      bin0 = r0 ? 1.0f : 0.0f;
      bin1 = r1 ? 1.0f : 0.0f;
    }
    outb[T * HDIM + lane]      = bin0;
    outb[T * HDIM + lane + 64] = bin1;
    outa[T * HDIM + lane]      = ba0;
    outa[T * HDIM + lane + 64] = ba1;
  }
}

extern "C" void kernel_launch(void* const* d_in, const int* in_sizes, int n_in,
                              void* d_out, int out_size, void* d_ws, size_t ws_size,
                              hipStream_t stream) {
  (void)in_sizes; (void)n_in; (void)ws_size; (void)out_size;
  const float* x   = (const float*)d_in[0];
  const float* Wr  = (const float*)d_in[1];
  const float* Wd  = (const float*)d_in[2];
  const float* gm  = (const float*)d_in[3];
  const float* bt  = (const float*)d_in[4];
  const float* rnn = (const float*)d_in[5];
  const float* gum = (const float*)d_in[6];
  float* outb = (float*)d_out;
  float* outa = outb + (size_t)NTOK * HDIM;   // tuple: (binary, binary_approx)

  _Float16* wh = (_Float16*)d_ws;             // 512 KB
  _Float16* wl = wh + (size_t)EDIM * DDIM;    // 512 KB

  conv_w<<<dim3(128), dim3(256), 0, stream>>>(Wr, wh, wl);
  fused_router<<<dim3(NTOK / TOKT), dim3(512), 0, stream>>>(
      x, wh, wl, Wd, gm, bt, rnn, gum, outb, outa);
}

// Round 5
// 256.112 us; speedup vs baseline: 1.0956x; 1.0956x over previous
//
#include <hip/hip_runtime.h>
#include <math.h>

#define NTOK   16384
#define DDIM   2048
#define EDIM   128
#define HDIM   128
#define TOKT   64
#define NRND   16            // rounds of 128 k each
#define KRND   128

typedef __attribute__((ext_vector_type(8)))  _Float16 half8;
typedef __attribute__((ext_vector_type(16))) float    f32x16;

#define MFMA32 __builtin_amdgcn_mfma_f32_32x32x16_f16

// b32-granule XOR swizzle for epilogue A[64][128]: conflict-free row+column.
__device__ __forceinline__ int swz(int t, int e) {
  return t * EDIM + ((e & 96) | ((e ^ t) & 31));
}

__device__ __forceinline__ void cvt8(const float4& a, const float4& b,
                                     half8& h, half8& l) {
#pragma unroll
  for (int m = 0; m < 4; ++m) {
    const float v = (&a.x)[m];
    const _Float16 hv = (_Float16)v;
    h[m] = hv; l[m] = (_Float16)((v - (float)hv) * 2048.0f);
  }
#pragma unroll
  for (int m = 0; m < 4; ++m) {
    const float v = (&b.x)[m];
    const _Float16 hv = (_Float16)v;
    h[m + 4] = hv; l[m + 4] = (_Float16)((v - (float)hv) * 2048.0f);
  }
}

// ---- W pre-convert: 32x32x16-fragment-ordered f16 hi/lo planes ----
// elem idx -> (nt, ks, lane, j); lane holds B[k=ks*16+(lane>>5)*8+j][n=nt*32+(lane&31)]
// = Wr[n][k], scaled by 32 (hi) and 32*2048 (lo) to dodge f16 denormals.
__global__ __launch_bounds__(256)
void conv_w(const float* __restrict__ Wr,
            _Float16* __restrict__ wh, _Float16* __restrict__ wl) {
  const int idx  = (int)blockIdx.x * 256 + (int)threadIdx.x;  // 0..32767
  const int lane = idx & 63;
  const int ks   = (idx >> 6) & 127;
  const int nt   = idx >> 13;                                 // 0..3
  const int n    = nt * 32 + (lane & 31);
  const int k0   = ks * 16 + (lane >> 5) * 8;
  half8 h, l;
#pragma unroll
  for (int j = 0; j < 8; ++j) {
    const float w = Wr[(size_t)n * DDIM + k0 + j] * 32.0f;
    const _Float16 hh = (_Float16)w;
    h[j] = hh;
    l[j] = (_Float16)((w - (float)hh) * 2048.0f);
  }
  *(half8*)(wh + (size_t)idx * 8) = h;
  *(half8*)(wl + (size_t)idx * 8) = l;
}

__global__ __launch_bounds__(1024, 4)
void fused_router(const float* __restrict__ x,
                  const _Float16* __restrict__ wsh,
                  const _Float16* __restrict__ wsl,
                  const float* __restrict__ Wd,
                  const float* __restrict__ gamma,
                  const float* __restrict__ beta,
                  const float* __restrict__ rnn,
                  const float* __restrict__ gum,
                  float* __restrict__ outb,
                  float* __restrict__ outa) {
  // GEMM phase: x ONLY in LDS, double-buffered 2 x 32 KB, one barrier/round.
  //   region (s,mt) at (s*2+mt)*2048 (+pl*1024); 16-B slot within region:
  //   slot = (koct*32+row) ^ s ^ (koct*4)  -- distinct super-banks for both
  //   the staging-write lane map and the fragment-read lane map.
  // W straight from fragment-ordered workspace (L2-resident, coalesced 1KB).
  // 16 waves: 2m x 4n tiles x 2-way K-split (kw). K-halves reduced via A.
  // Epilogue overlays: A = bytes [0,32K), G4 = [32K,64K).
  __shared__ char smraw[65536];
  char* const sm = smraw;
  float* const A  = (float*)smraw;
  float* const G4 = (float*)(smraw + 32768);

  const int tid  = (int)threadIdx.x;
  const int wv   = __builtin_amdgcn_readfirstlane(tid >> 6);  // 0..15
  const int lane = tid & 63;
  const int t0   = (int)blockIdx.x * TOKT;

  // wave -> one 32x32 C tile + K-half
  const int kw  = wv >> 3;          // 0/1: K-half
  const int mt  = (wv >> 2) & 1;    // token half
  const int nt  = wv & 3;           // e quarter
  const int kw4 = kw * 4;

  // x staging: thread -> (token, 8 consecutive k); 32 B global -> 2 x 16 B LDS
  const int s_tok = (tid & 3) + ((tid >> 6) << 2);   // 4 tokens per wave
  const int s_kq  = (tid >> 2) & 15;                 // 8-k octant within round
  const int s_s   = s_kq >> 1;
  const int s_ko  = s_kq & 1;
  const float* xg = x + (size_t)(t0 + s_tok) * DDIM + s_kq * 8;
  const int wbase = (s_s * 2 + (s_tok >> 5)) * 2048;   // + pl*1024
  const int wslot = ((s_ko * 32 + (s_tok & 31)) ^ s_s ^ (s_ko * 4)) * 16;

  // W direct-to-reg: elem offset = ((nt*128 + ks)*64 + lane)*8
  const size_t wbf = (size_t)nt * 65536 + (size_t)lane * 8;

  f32x16 hh, cr;
#pragma unroll
  for (int g = 0; g < 16; ++g) { hh[g] = 0.0f; cr[g] = 0.0f; }

  // ---- prologue: stage round 0 into buffer 0 ----
  {
    const float4 a0 = *(const float4*)(xg + 0);
    const float4 a1 = *(const float4*)(xg + 4);
    half8 h, l;
    cvt8(a0, a1, h, l);
    *(half8*)(sm + wbase + wslot)        = h;
    *(half8*)(sm + wbase + 1024 + wslot) = l;
  }

  for (int r = 0; r < NRND; ++r) {
    __syncthreads();                       // buf (r&1) visible; (r&1)^1 free
    float4 p0, p1;
    if (r + 1 < NRND) {                    // issue next-round x loads early
      const float* xn = xg + (r + 1) * KRND;
      p0 = *(const float4*)(xn + 0);
      p1 = *(const float4*)(xn + 4);
    }
    const char* bb = sm + (r & 1) * 32768;
#pragma unroll
    for (int i = 0; i < 4; ++i) {
      const int s  = kw4 + i;
      const int fb = (s * 2 + mt) * 2048;
      const int ai = ((lane ^ s ^ ((lane >> 5) << 2)) << 4);
      const half8 ah = *(const half8*)(bb + fb + ai);
      const half8 al = *(const half8*)(bb + fb + 1024 + ai);
      const size_t wo = wbf + (size_t)(r * 8 + s) * 512;
      const half8 bh = *(const half8*)(wsh + wo);
      const half8 bl = *(const half8*)(wsl + wo);
      hh = MFMA32(ah, bh, hh, 0, 0, 0);
      cr = MFMA32(ah, bl, cr, 0, 0, 0);
      cr = MFMA32(al, bh, cr, 0, 0, 0);
    }
    if (r + 1 < NRND) {                    // convert + write into free buffer
      half8 h, l;
      cvt8(p0, p1, h, l);
      char* dst = sm + ((r + 1) & 1) * 32768;
      *(half8*)(dst + wbase + wslot)        = h;
      *(half8*)(dst + wbase + 1024 + wslot) = l;
    }
  }
  __syncthreads();                         // GEMM LDS dead

  // ---- K-split reduce + unscale + rnn into A ----
  // 32x32 C/D layout: col = lane&31, row = (g&3) + 8*(g>>2) + 4*(lane>>5)
  const int e = nt * 32 + (lane & 31);
  if (kw == 0) {
#pragma unroll
    for (int g = 0; g < 16; ++g) {
      const int row = (g & 3) + 8 * (g >> 2) + 4 * (lane >> 5);
      A[swz(mt * 32 + row, e)] =
          hh[g] * (1.0f / 32.0f) + cr[g] * (1.0f / 65536.0f);
    }
  }
  __syncthreads();
  if (kw == 1) {
    const float rv = rnn[e];
#pragma unroll
    for (int g = 0; g < 16; ++g) {
      const int row = (g & 3) + 8 * (g >> 2) + 4 * (lane >> 5);
      A[swz(mt * 32 + row, e)] +=
          hh[g] * (1.0f / 32.0f) + cr[g] * (1.0f / 65536.0f) + rv;
    }
  }
  __syncthreads();

  // ---- LayerNorm + exact GELU: 4 tokens per wave; G -> G4 (float4-swizzled) ----
  const int e0 = wv * 8;                  // decoder e-mapping
  {
    const float gm0 = gamma[lane], gm1 = gamma[lane + 64];
    const float bt0 = beta[lane],  bt1 = beta[lane + 64];
    for (int tt = wv * 4; tt < wv * 4 + 4; ++tt) {
      const float v0 = A[swz(tt, lane)];
      const float v1 = A[swz(tt, lane + 64)];
      float s = v0 + v1;
#pragma unroll
      for (int m = 32; m; m >>= 1) s += __shfl_xor(s, m);
      const float mu = s * (1.0f / 128.0f);
      const float d0 = v0 - mu, d1 = v1 - mu;
      float q = d0 * d0 + d1 * d1;
#pragma unroll
      for (int m = 32; m; m >>= 1) q += __shfl_xor(q, m);
      const float rstd = 1.0f / sqrtf(q * (1.0f / 128.0f) + 1e-5f);
      const float h0v = d0 * rstd * gm0 + bt0;
      const float h1v = d1 * rstd * gm1 + bt1;
      const float g0 = 0.5f * h0v * (1.0f + erff(h0v * 0.70710678118654752f));
      const float g1 = 0.5f * h1v * (1.0f + erff(h1v * 0.70710678118654752f));
      const int e0a = lane, e1a = lane + 64;
      G4[(tt * 32 + (((e0a >> 2) ^ (tt & 31)))) * 4 + (e0a & 3)] = g0;
      G4[(tt * 32 + (((e1a >> 2) ^ (tt & 31)))) * 4 + (e1a & 3)] = g1;
    }
  }
  __syncthreads();

  // ---- decoder GEMM: wave = 8 h-rows x 64 tokens (lane = token) ----
  {
    float acc2[8];
#pragma unroll
    for (int j = 0; j < 8; ++j) acc2[j] = 0.0f;
    const float4* wd4 = (const float4*)(Wd + (size_t)e0 * EDIM);  // uniform
#pragma unroll 2
    for (int kg = 0; kg < EDIM / 4; ++kg) {
      const float4 gv = *(const float4*)&G4[(lane * 32 + (kg ^ (lane & 31))) * 4];
#pragma unroll
      for (int j = 0; j < 8; ++j) {
        const float4 w = wd4[(size_t)j * (EDIM / 4) + kg];
        acc2[j] = fmaf(gv.x, w.x,
                  fmaf(gv.y, w.y,
                  fmaf(gv.z, w.z,
                  fmaf(gv.w, w.w, acc2[j]))));
      }
    }
    __syncthreads();                 // all G4 reads done block-wide
#pragma unroll
    for (int j = 0; j < 8; ++j) A[swz(lane, e0 + j)] = acc2[j];
  }
  __syncthreads();

  // ---- gumbel-sigmoid, exact top-k (value then lower-index), output ----
  for (int tt = wv * 4; tt < wv * 4 + 4; ++tt) {
    const size_t T = (size_t)(t0 + tt);
    const float l0 = A[swz(tt, lane)];
    const float l1 = A[swz(tt, lane + 64)];
    const float gn0 = gum[T * HDIM + lane];
    const float gn1 = gum[T * HDIM + lane + 64];
    const float z0 = (l0 + gn0 + 3.0f) * 2.5f;
    const float z1 = (l1 + gn1 + 3.0f) * 2.5f;
    const float ba0 = 1.0f / (1.0f + expf(-z0));
    const float ba1 = 1.0f / (1.0f + expf(-z1));
    const unsigned ub0 = __float_as_uint(ba0);   // ba in (0,1]: bits monotone
    const unsigned ub1 = __float_as_uint(ba1);
    const int r0 = ba0 > 0.5f;                   // round: 0.5 -> 0
    const int r1 = ba1 > 0.5f;
    const int cnt = __popcll(__ballot(r0)) + __popcll(__ballot(r1));
    float bin0, bin1;
    if (cnt > 32) {
      // cnt>32 => 32nd-largest ba > 0.5 => its bits in (0x3F000000, 0x3F800000]
      // so fix the prefix and radix-select over the low 24 bits only.
      unsigned v = 0x3F000000u;
#pragma unroll
      for (int b = 23; b >= 0; --b) {
        const unsigned cand = v | (1u << b);
        const int cc = __popcll(__ballot(ub0 >= cand)) + __popcll(__ballot(ub1 >= cand));
        if (cc >= 32) v = cand;
      }
      const int cgt = __popcll(__ballot(ub0 > v)) + __popcll(__ballot(ub1 > v));
      const int r = 32 - cgt;                     // tied slots; lower index wins
      const unsigned long long t0b = __ballot(ub0 == v);
      const unsigned long long t1b = __ballot(ub1 == v);
      const int n0 = __popcll(t0b);
      const unsigned long long mlt = (1ull << lane) - 1ull;
      const int rk0 = __popcll(t0b & mlt);
      const int rk1 = n0 + __popcll(t1b & mlt);
      bin0 = (ub0 > v || (ub0 == v && rk0 < r)) ? 1.0f : 0.0f;
      bin1 = (ub1 > v || (ub1 == v && rk1 < r)) ? 1.0f : 0.0f;
    } else if (cnt == 0) {
      float m = fmaxf(ba0, ba1);
#pragma unroll
      for (int mm = 32; mm; mm >>= 1) m = fmaxf(m, __shfl_xor(m, mm));
      const unsigned long long e0b = __ballot(ba0 == m);
      const unsigned long long e1b = __ballot(ba1 == m);
      const int hstar = e0b ? (__ffsll((unsigned long long)e0b) - 1)
                            : (64 + __ffsll((unsigned long long)e1b) - 1);
      bin0 = (lane == hstar) ? 1.0f : 0.0f;
      bin1 = (lane + 64 == hstar) ? 1.0f : 0.0f;
    } else {
      bin0 = r0 ? 1.0f : 0.0f;
      bin1 = r1 ? 1.0f : 0.0f;
    }
    outb[T * HDIM + lane]      = bin0;
    outb[T * HDIM + lane + 64] = bin1;
    outa[T * HDIM + lane]      = ba0;
    outa[T * HDIM + lane + 64] = ba1;
  }
}

extern "C" void kernel_launch(void* const* d_in, const int* in_sizes, int n_in,
                              void* d_out, int out_size, void* d_ws, size_t ws_size,
                              hipStream_t stream) {
  (void)in_sizes; (void)n_in; (void)ws_size; (void)out_size;
  const float* x   = (const float*)d_in[0];
  const float* Wr  = (const float*)d_in[1];
  const float* Wd  = (const float*)d_in[2];
  const float* gm  = (const float*)d_in[3];
  const float* bt  = (const float*)d_in[4];
  const float* rnn = (const float*)d_in[5];
  const float* gum = (const float*)d_in[6];
  float* outb = (float*)d_out;
  float* outa = outb + (size_t)NTOK * HDIM;   // tuple: (binary, binary_approx)

  _Float16* wh = (_Float16*)d_ws;             // 512 KB
  _Float16* wl = wh + (size_t)EDIM * DDIM;    // 512 KB

  conv_w<<<dim3(128), dim3(256), 0, stream>>>(Wr, wh, wl);
  fused_router<<<dim3(NTOK / TOKT), dim3(1024), 0, stream>>>(
      x, wh, wl, Wd, gm, bt, rnn, gum, outb, outa);
}